// Round 1
// baseline (9768.858 us; speedup 1.0000x reference)
//
#include <hip/hip_runtime.h>
#include <cstddef>

#define TPB 256

// ---------------- conv 3x3 SAME, NCHW, OIHW weights, optional ReLU ----------
__global__ __launch_bounds__(TPB) void k_conv3x3(
    const float* __restrict__ in, const float* __restrict__ w,
    const float* __restrict__ bias, float* __restrict__ out,
    int Cin, int H, int W, int do_relu)
{
    int p = blockIdx.x * TPB + threadIdx.x;
    int HW = H * W;
    if (p >= HW) return;
    int co = blockIdx.y;
    int y = p / W, x = p % W;
    float acc = bias[co];
    const float* wp = w + (size_t)co * Cin * 9;
    for (int ci = 0; ci < Cin; ++ci) {
        const float* ip = in + (size_t)ci * HW;
        #pragma unroll
        for (int ky = 0; ky < 3; ++ky) {
            int yy = y + ky - 1;
            if (yy < 0 || yy >= H) continue;
            const float* ipr = ip + yy * W;
            #pragma unroll
            for (int kx = 0; kx < 3; ++kx) {
                int xx = x + kx - 1;
                if (xx < 0 || xx >= W) continue;
                acc = fmaf(ipr[xx], wp[ky * 3 + kx], acc);
            }
        }
        wp += 9;
    }
    if (do_relu) acc = fmaxf(acc, 0.f);
    out[(size_t)co * HW + p] = acc;
}

// ---------------- maxpool 2x2 stride 2 ----------------
__global__ __launch_bounds__(TPB) void k_maxpool2(
    const float* __restrict__ in, float* __restrict__ out, int C, int H, int W)
{
    int oh = H >> 1, ow = W >> 1;
    int tot = C * oh * ow;
    int idx = blockIdx.x * TPB + threadIdx.x;
    if (idx >= tot) return;
    int c = idx / (oh * ow);
    int r = idx % (oh * ow);
    int y = r / ow, x = r % ow;
    const float* ip = in + (size_t)c * H * W + (size_t)(2 * y) * W + 2 * x;
    out[idx] = fmaxf(fmaxf(ip[0], ip[1]), fmaxf(ip[W], ip[W + 1]));
}

// ---------------- pad(1) + NCHW->node-major transpose: X0[n][c], n over 66x66
__global__ __launch_bounds__(TPB) void k_build_nodes(
    const float* __restrict__ p2, float* __restrict__ X0)
{
    int idx = blockIdx.x * TPB + threadIdx.x;   // over 4356*128
    if (idx >= 4356 * 128) return;
    int n = idx >> 7, c = idx & 127;
    int i = n / 66, j = n % 66;
    float v = 0.f;
    if (i >= 1 && i <= 64 && j >= 1 && j <= 64)
        v = p2[(size_t)c * 4096 + (i - 1) * 64 + (j - 1)];
    X0[idx] = v;
}

// ---------------- graph aggregation: (self + valid 4-nbrs) / (1 + #valid) ---
__global__ __launch_bounds__(TPB) void k_gagg(
    const float* __restrict__ X, float* __restrict__ agg, int C)
{
    int idx = blockIdx.x * TPB + threadIdx.x;   // over 4356*C, c fastest
    if (idx >= 4356 * C) return;
    int n = idx / C;
    int i = n / 66, j = n % 66;
    float s = X[idx];
    float cnt = 1.f;
    if (i > 0)  { s += X[idx - 66 * C]; cnt += 1.f; }
    if (i < 65) { s += X[idx + 66 * C]; cnt += 1.f; }
    if (j > 0)  { s += X[idx - C];      cnt += 1.f; }
    if (j < 65) { s += X[idx + C];      cnt += 1.f; }
    agg[idx] = s / cnt;
}

// ---------------- node matmul: Y = relu(A @ W + b) (+ resid), A:[N][C], W:[C][D]
template<int TN>
__global__ __launch_bounds__(TPB) void k_node_mm(
    const float* __restrict__ A, const float* __restrict__ Wm,
    const float* __restrict__ bias, const float* __restrict__ resid,
    float* __restrict__ Y, int N, int C, int D)
{
    int d = blockIdx.x * TPB + threadIdx.x;     // D is a multiple of 256
    int n0 = blockIdx.y * TN;
    const float* ap[TN];
    #pragma unroll
    for (int t = 0; t < TN; ++t) {
        int n = n0 + t; if (n > N - 1) n = N - 1;   // clamp for safe reads
        ap[t] = A + (size_t)n * C;
    }
    float acc[TN];
    #pragma unroll
    for (int t = 0; t < TN; ++t) acc[t] = 0.f;
    for (int c = 0; c < C; ++c) {
        float wv = Wm[(size_t)c * D + d];
        #pragma unroll
        for (int t = 0; t < TN; ++t)
            acc[t] = fmaf(ap[t][c], wv, acc[t]);
    }
    float bv = bias[d];
    #pragma unroll
    for (int t = 0; t < TN; ++t) {
        int n = n0 + t;
        if (n < N) {
            float v = fmaxf(acc[t] + bv, 0.f);
            if (resid) v += resid[(size_t)n * D + d];
            Y[(size_t)n * D + d] = v;
        }
    }
}

// ---------------- crop 66x66 node-major (256ch) -> NCHW 256x64x64 -----------
__global__ __launch_bounds__(TPB) void k_crop(
    const float* __restrict__ Xd, float* __restrict__ fe)
{
    int idx = blockIdx.x * TPB + threadIdx.x;   // over 64*64*256, c fastest
    if (idx >= 64 * 64 * 256) return;
    int c = idx & 255;
    int pix = idx >> 8;
    int y = pix >> 6, x = pix & 63;
    float v = Xd[(size_t)((y + 1) * 66 + (x + 1)) * 256 + c];
    fe[(size_t)c * 4096 + y * 64 + x] = v;
}

// ---------------- convT 2x2 stride 2 VALID, HWIO weights (taps flipped) -----
__global__ __launch_bounds__(TPB) void k_convT(
    const float* __restrict__ in, const float* __restrict__ w,
    const float* __restrict__ bias, float* __restrict__ out,
    int C, int O, int H, int W, int coff)
{
    int OH = 2 * H, OW = 2 * W;
    int p = blockIdx.x * TPB + threadIdx.x;
    if (p >= OH * OW) return;
    int o = blockIdx.y;
    int oy = p / OW, ox = p % OW;
    int iy = oy >> 1, ix = ox >> 1;
    int ky = 1 - (oy & 1), kx = 1 - (ox & 1);   // jax conv_transpose tap flip
    const float* wp = w + (size_t)(ky * 2 + kx) * C * O + o;
    const float* ip = in + (size_t)iy * W + ix;
    float acc = bias[o];
    for (int c = 0; c < C; ++c)
        acc = fmaf(ip[(size_t)c * H * W], wp[(size_t)c * O], acc);
    out[(size_t)(coff + o) * OH * OW + p] = acc;
}

// ---------------- plain copy (for channel-concat) ---------------------------
__global__ __launch_bounds__(TPB) void k_copy(
    const float* __restrict__ src, float* __restrict__ dst, int n)
{
    int i = blockIdx.x * TPB + threadIdx.x;
    if (i < n) dst[i] = src[i];
}

extern "C" void kernel_launch(void* const* d_in, const int* in_sizes, int n_in,
                              void* d_out, int out_size, void* d_ws, size_t ws_size,
                              hipStream_t stream) {
    const float* x    = (const float*)d_in[0];
    const float* d1w1 = (const float*)d_in[1];  const float* d1b1 = (const float*)d_in[2];
    const float* d1w2 = (const float*)d_in[3];  const float* d1b2 = (const float*)d_in[4];
    const float* d2w1 = (const float*)d_in[5];  const float* d2b1 = (const float*)d_in[6];
    const float* d2w2 = (const float*)d_in[7];  const float* d2b2 = (const float*)d_in[8];
    const float* md1w = (const float*)d_in[9];  const float* md1b = (const float*)d_in[10];
    const float* md2w = (const float*)d_in[11]; const float* md2b = (const float*)d_in[12];
    const float* mbw  = (const float*)d_in[13]; const float* mbb  = (const float*)d_in[14];
    const float* mu1w = (const float*)d_in[15]; const float* mu1b = (const float*)d_in[16];
    const float* mu2w = (const float*)d_in[17]; const float* mu2b = (const float*)d_in[18];
    const float* u3tw = (const float*)d_in[19]; const float* u3tb = (const float*)d_in[20];
    const float* u3w1 = (const float*)d_in[21]; const float* u3b1 = (const float*)d_in[22];
    const float* u3w2 = (const float*)d_in[23]; const float* u3b2 = (const float*)d_in[24];
    const float* u4tw = (const float*)d_in[25]; const float* u4tb = (const float*)d_in[26];
    const float* u4w1 = (const float*)d_in[27]; const float* u4b1 = (const float*)d_in[28];
    const float* u4w2 = (const float*)d_in[29]; const float* u4b2 = (const float*)d_in[30];
    const float* ow   = (const float*)d_in[31]; const float* ob   = (const float*)d_in[32];
    float* out = (float*)d_out;

    float* W0 = (float*)d_ws;
    // persistent skip buffers
    float* b1 = W0;                          // 64*256*256  = 4194304
    float* b2 = W0 + 4194304;                // 128*128*128 = 2097152
    const size_t S0 = 6291456;               // scratch arena base (floats)
    // stage A/B transients
    float* t1 = W0 + S0;                     // 4194304
    float* p1 = W0 + S0;                     // 1048576 (after t1 dead)
    float* t2 = W0 + S0 + 1048576;           // 2097152
    // stage C (graph)
    float* p2  = W0 + S0;                    // 524288
    float* X0  = W0 + S0 + 524288;           // 4356*128  = 557568
    float* bp1 = X0 + 557568;                // 4356*256  = 1115136
    float* bp2 = bp1 + 1115136;              // 4356*512  = 2230272
    float* Xb  = bp2 + 2230272;              // 4356*1024 = 4460544
    float* Xc  = Xb + 4460544;               // 4356*512  = 2230272
    float* Xd  = Xc + 2230272;               // 4356*256  = 1115136
    float* agg = Xd + 1115136;               // 4356*1024 = 4460544
    // stage D (graph buffers dead as consumed)
    float* fe256 = W0 + S0;                  // 256*64*64 = 1048576
    float* cat3  = W0 + S0 + 1048576;        // 256*128*128 = 4194304
    float* v3a   = W0 + S0 + 5242880;        // 128*128*128 = 2097152
    float* v3b   = W0 + S0 + 7340032;        // 2097152
    // stage E
    float* cat4  = W0 + S0 + 9437184;        // 128*256*256 = 8388608
    float* v4a   = W0 + S0;                  // 64*256*256 = 4194304
    float* v4b   = W0 + S0 + 4194304;        // 4194304
    // peak ws use: S0+17825792 floats = ~96.5 MB

    dim3 blk(TPB);

    // encoder block 1 @256^2
    k_conv3x3<<<dim3(256, 64), blk, 0, stream>>>(x,  d1w1, d1b1, t1, 3,  256, 256, 1);
    k_conv3x3<<<dim3(256, 64), blk, 0, stream>>>(t1, d1w2, d1b2, b1, 64, 256, 256, 1);
    k_maxpool2<<<dim3(4096), blk, 0, stream>>>(b1, p1, 64, 256, 256);
    // encoder block 2 @128^2
    k_conv3x3<<<dim3(64, 128), blk, 0, stream>>>(p1, d2w1, d2b1, t2, 64,  128, 128, 1);
    k_conv3x3<<<dim3(64, 128), blk, 0, stream>>>(t2, d2w2, d2b2, b2, 128, 128, 128, 1);
    k_maxpool2<<<dim3(2048), blk, 0, stream>>>(b2, p2, 128, 128, 128);
    // graph part on 66x66 padded grid
    k_build_nodes<<<dim3(2178), blk, 0, stream>>>(p2, X0);

    k_gagg<<<dim3((4356 * 128 + TPB - 1) / TPB), blk, 0, stream>>>(X0, agg, 128);
    k_node_mm<16><<<dim3(1, 273), blk, 0, stream>>>(agg, md1w, md1b, nullptr, bp1, 4356, 128, 256);
    k_gagg<<<dim3((4356 * 256 + TPB - 1) / TPB), blk, 0, stream>>>(bp1, agg, 256);
    k_node_mm<16><<<dim3(2, 273), blk, 0, stream>>>(agg, md2w, md2b, nullptr, bp2, 4356, 256, 512);
    k_gagg<<<dim3((4356 * 512 + TPB - 1) / TPB), blk, 0, stream>>>(bp2, agg, 512);
    k_node_mm<16><<<dim3(4, 273), blk, 0, stream>>>(agg, mbw, mbb, nullptr, Xb, 4356, 512, 1024);
    k_gagg<<<dim3((4356 * 1024 + TPB - 1) / TPB), blk, 0, stream>>>(Xb, agg, 1024);
    k_node_mm<16><<<dim3(2, 273), blk, 0, stream>>>(agg, mu1w, mu1b, bp2, Xc, 4356, 1024, 512);
    k_gagg<<<dim3((4356 * 512 + TPB - 1) / TPB), blk, 0, stream>>>(Xc, agg, 512);
    k_node_mm<16><<<dim3(1, 273), blk, 0, stream>>>(agg, mu2w, mu2b, bp1, Xd, 4356, 512, 256);

    k_crop<<<dim3(4096), blk, 0, stream>>>(Xd, fe256);

    // decoder stage 3 @128^2: cat(b2, convT(fe256)) -> conv -> conv
    k_copy<<<dim3(8192), blk, 0, stream>>>(b2, cat3, 2097152);
    k_convT<<<dim3(64, 128), blk, 0, stream>>>(fe256, u3tw, u3tb, cat3, 256, 128, 64, 64, 128);
    k_conv3x3<<<dim3(64, 128), blk, 0, stream>>>(cat3, u3w1, u3b1, v3a, 256, 128, 128, 1);
    k_conv3x3<<<dim3(64, 128), blk, 0, stream>>>(v3a, u3w2, u3b2, v3b, 128, 128, 128, 1);

    // decoder stage 4 @256^2: cat(b1, convT(v3b)) -> conv -> conv
    k_copy<<<dim3(16384), blk, 0, stream>>>(b1, cat4, 4194304);
    k_convT<<<dim3(256, 64), blk, 0, stream>>>(v3b, u4tw, u4tb, cat4, 128, 64, 128, 128, 64);
    k_conv3x3<<<dim3(256, 64), blk, 0, stream>>>(cat4, u4w1, u4b1, v4a, 128, 256, 256, 1);
    k_conv3x3<<<dim3(256, 64), blk, 0, stream>>>(v4a, u4w2, u4b2, v4b, 64, 256, 256, 1);

    // output conv 64->1, no relu
    k_conv3x3<<<dim3(256, 1), blk, 0, stream>>>(v4b, ow, ob, out, 64, 256, 256, 0);
}

// Round 2
// 511.013 us; speedup vs baseline: 19.1167x; 19.1167x over previous
//
#include <hip/hip_runtime.h>
#include <cstddef>

#define TPB 256

typedef __attribute__((ext_vector_type(8))) short short8;
typedef __attribute__((ext_vector_type(4))) float f32x4;

__device__ inline unsigned short f2bf(float f) {
    unsigned int u = __builtin_bit_cast(unsigned int, f);
    u += 0x7fffu + ((u >> 16) & 1u);
    return (unsigned short)(u >> 16);
}
__device__ inline float bf2f(unsigned short h) {
    unsigned int u = ((unsigned int)h) << 16;
    return __builtin_bit_cast(float, u);
}

struct TapOffs { int o[9]; };

// ---------------------------------------------------------------------------
// Generic MFMA GEMM: out[m][n] = act( sum_taps A[m+tapoff][k] * Wf[k][n] + b )
// A: bf16, row stride Cs (channels-last). Block tile: 64m x 64n. 4 waves,
// wave w handles m-rows [w*16, w*16+16) x all 64 n.
// Wf packed so each lane's B-frag is one contiguous 16B load:
//   Wf[((tap*KC+q)*NTtot + ntile)*512 + lane*8 + j] = W[k=q*32+(lane>>4)*8+j][n=ntile*16+(lane&15)]
// mfma_f32_16x16x32_bf16 layouts (HW-verified): A[m=lane&15][k=(lane>>4)*8+j],
// B[k][n=lane&15], D: col=lane&15 (n), row=(lane>>4)*4+reg (m).
// ---------------------------------------------------------------------------
__global__ __launch_bounds__(TPB) void k_gemm(
    const unsigned short* __restrict__ A0, const unsigned short* __restrict__ Wf,
    const float* __restrict__ bias, const unsigned short* __restrict__ resid, int RS,
    unsigned short* __restrict__ O0,
    int Cs, int AP, int xt, int OMS, int OP,
    int KC, int T, TapOffs toffs, int NTtot, int relu)
{
    int lane = threadIdx.x & 63, wave = threadIdx.x >> 6;
    int ml = lane & 15, kq = lane >> 4;
    int t = blockIdx.x, nb = blockIdx.y;
    int y = t / xt, xb = t - y * xt;

    const unsigned short* Arow = A0 + (size_t)y * AP
        + (size_t)(xb * 64 + wave * 16 + ml) * Cs + kq * 8;
    const unsigned short* WbB = Wf + (size_t)(nb * 4) * 512 + lane * 8;

    f32x4 acc[4];
    #pragma unroll
    for (int nt = 0; nt < 4; ++nt) acc[nt] = (f32x4){0.f, 0.f, 0.f, 0.f};

    for (int tp = 0; tp < T; ++tp) {
        const unsigned short* Atap = Arow + toffs.o[tp];
        const unsigned short* Wt = WbB + (size_t)(tp * KC) * NTtot * 512;
        for (int q = 0; q < KC; ++q) {
            short8 a = *(const short8*)(Atap + q * 32);
            const unsigned short* Wq = Wt + (size_t)q * NTtot * 512;
            #pragma unroll
            for (int nt = 0; nt < 4; ++nt) {
                short8 b = *(const short8*)(Wq + nt * 512);
                acc[nt] = __builtin_amdgcn_mfma_f32_16x16x32_bf16(a, b, acc[nt], 0, 0, 0);
            }
        }
    }

    unsigned short* Ot = O0 + (size_t)y * OP
        + (size_t)(xb * 64 + wave * 16 + kq * 4) * OMS + (size_t)nb * 64;
    int mg0 = t * 64 + wave * 16 + kq * 4;
    #pragma unroll
    for (int nt = 0; nt < 4; ++nt) {
        int ng = nb * 64 + nt * 16 + ml;
        float bv = bias[ng];
        #pragma unroll
        for (int r = 0; r < 4; ++r) {
            float v = acc[nt][r] + bv;
            if (relu) v = fmaxf(v, 0.f);
            if (resid) v += bf2f(resid[(size_t)(mg0 + r) * RS + ng]);
            Ot[(size_t)r * OMS + nt * 16 + ml] = f2bf(v);
        }
    }
}

// ---------------- weight packing into B-fragment order ----------------------
// mode 0: conv OIHW [N][K][3][3], T=9 taps
// mode 1: node W [K][N], T=1
// mode 2: convT HWIO [2][2][K][N], T=4 taps (tap=ky*2+kx)
// mode 3: conv1 im2col-padded: K=32 (27 real: k=tap*3+c), OIHW [N][3][3][3]
__global__ __launch_bounds__(TPB) void k_pack(
    const float* __restrict__ w, unsigned short* __restrict__ o,
    int mode, int KC, int NT, int K, int N, int total)
{
    int idx = blockIdx.x * TPB + threadIdx.x;
    if (idx >= total) return;
    int j = idx & 7, l = (idx >> 3) & 63;
    int r = idx >> 9;
    int ntg = r % NT; int r2 = r / NT;
    int q = r2 % KC; int tp = r2 / KC;
    int k = q * 32 + (l >> 4) * 8 + j;
    int n = ntg * 16 + (l & 15);
    float v = 0.f;
    if (mode == 0) { int ky = tp / 3, kx = tp % 3; v = w[(size_t)(n * K + k) * 9 + ky * 3 + kx]; }
    else if (mode == 1) { v = w[(size_t)k * N + n]; }
    else if (mode == 2) { v = w[((size_t)tp * K + k) * N + n]; }
    else { if (k < 27) { int tap = k / 3, c = k % 3; int ky = tap / 3, kx = tap % 3;
                         v = w[((n * 3 + c) * 3 + ky) * 3 + kx]; } }
    o[idx] = f2bf(v);
}

// ---------------- conv1 im2col: x fp32 [3][256][256] -> xcol bf16 [65536][32]
__global__ __launch_bounds__(TPB) void k_im2col(
    const float* __restrict__ x, unsigned short* __restrict__ xcol)
{
    int idx = blockIdx.x * TPB + threadIdx.x;
    if (idx >= 65536 * 32) return;
    int k = idx & 31, m = idx >> 5;
    int y = m >> 8, xx = m & 255;
    float v = 0.f;
    if (k < 27) {
        int tap = k / 3, c = k - tap * 3;
        int ty = tap / 3, tx = tap % 3;
        int yy = y + ty - 1, xp = xx + tx - 1;
        if (yy >= 0 && yy < 256 && xp >= 0 && xp < 256)
            v = x[c * 65536 + yy * 256 + xp];
    }
    xcol[idx] = f2bf(v);
}

// ---------------- maxpool 2x2 channels-last (strided in/out) ----------------
__global__ __launch_bounds__(TPB) void k_maxpool(
    const unsigned short* __restrict__ inI, unsigned short* __restrict__ outI,
    int Wo, int C4, int CsIn, int inPitch, int CsOut, int outPitch, int total)
{
    int idx = blockIdx.x * TPB + threadIdx.x;
    if (idx >= total) return;
    int c4 = idx % C4; int p = idx / C4;
    int x = p % Wo, y = p / Wo;
    const unsigned short* ip = inI + (size_t)(2 * y) * inPitch + (size_t)(2 * x) * CsIn + c4 * 4;
    ushort4 a = *(const ushort4*)(ip);
    ushort4 b = *(const ushort4*)(ip + CsIn);
    ushort4 c = *(const ushort4*)(ip + inPitch);
    ushort4 d = *(const ushort4*)(ip + inPitch + CsIn);
    ushort4 o;
    o.x = f2bf(fmaxf(fmaxf(bf2f(a.x), bf2f(b.x)), fmaxf(bf2f(c.x), bf2f(d.x))));
    o.y = f2bf(fmaxf(fmaxf(bf2f(a.y), bf2f(b.y)), fmaxf(bf2f(c.y), bf2f(d.y))));
    o.z = f2bf(fmaxf(fmaxf(bf2f(a.z), bf2f(b.z)), fmaxf(bf2f(c.z), bf2f(d.z))));
    o.w = f2bf(fmaxf(fmaxf(bf2f(a.w), bf2f(b.w)), fmaxf(bf2f(c.w), bf2f(d.w))));
    *(ushort4*)(outI + (size_t)y * outPitch + (size_t)x * CsOut + c4 * 4) = o;
}

// ---------------- graph aggregation on 66x66 grid, node-major bf16 ----------
__global__ __launch_bounds__(TPB) void k_gagg(
    const unsigned short* __restrict__ X, unsigned short* __restrict__ agg,
    int C, int total)
{
    int idx = blockIdx.x * TPB + threadIdx.x;
    if (idx >= total) return;
    int C4 = C >> 2;
    int c4 = idx % C4; int n = idx / C4;
    int i = n / 66, j = n - i * 66;
    size_t base = (size_t)n * C + c4 * 4;
    ushort4 s = *(const ushort4*)(X + base);
    float v0 = bf2f(s.x), v1 = bf2f(s.y), v2 = bf2f(s.z), v3 = bf2f(s.w);
    float cnt = 1.f;
    if (i > 0)  { ushort4 u = *(const ushort4*)(X + base - (size_t)66 * C);
                  v0 += bf2f(u.x); v1 += bf2f(u.y); v2 += bf2f(u.z); v3 += bf2f(u.w); cnt += 1.f; }
    if (i < 65) { ushort4 u = *(const ushort4*)(X + base + (size_t)66 * C);
                  v0 += bf2f(u.x); v1 += bf2f(u.y); v2 += bf2f(u.z); v3 += bf2f(u.w); cnt += 1.f; }
    if (j > 0)  { ushort4 u = *(const ushort4*)(X + base - C);
                  v0 += bf2f(u.x); v1 += bf2f(u.y); v2 += bf2f(u.z); v3 += bf2f(u.w); cnt += 1.f; }
    if (j < 65) { ushort4 u = *(const ushort4*)(X + base + C);
                  v0 += bf2f(u.x); v1 += bf2f(u.y); v2 += bf2f(u.z); v3 += bf2f(u.w); cnt += 1.f; }
    float inv = 1.f / cnt;
    ushort4 o;
    o.x = f2bf(v0 * inv); o.y = f2bf(v1 * inv); o.z = f2bf(v2 * inv); o.w = f2bf(v3 * inv);
    *(ushort4*)(agg + base) = o;
}

// ---------------- zero the 1-px ring of a padded channels-last buffer -------
__global__ __launch_bounds__(TPB) void k_zero_ring(
    unsigned short* __restrict__ buf, int W2, int H2, int Cs, int total)
{
    int idx = blockIdx.x * TPB + threadIdx.x;
    if (idx >= total) return;
    int topbot = 2 * W2 * Cs;
    int iy, ix, c;
    if (idx < topbot) {
        int r = idx / (W2 * Cs); int rest = idx - r * (W2 * Cs);
        iy = r ? (H2 - 1) : 0; ix = rest / Cs; c = rest - (rest / Cs) * Cs;
    } else {
        int idx2 = idx - topbot;
        int per = (H2 - 2) * Cs;
        int side = idx2 / per; int rest = idx2 - side * per;
        iy = 1 + rest / Cs; ix = side ? (W2 - 1) : 0; c = rest - (rest / Cs) * Cs;
    }
    buf[((size_t)iy * W2 + ix) * Cs + c] = 0;
}

// ---------------- final conv 64->1, fp32 out --------------------------------
__global__ __launch_bounds__(TPB) void k_outconv(
    const unsigned short* __restrict__ vI, const float* __restrict__ ow,
    const float* __restrict__ ob, float* __restrict__ out)
{
    __shared__ float wl[576];
    for (int i = threadIdx.x; i < 576; i += TPB) wl[i] = ow[i];
    __syncthreads();
    int p = blockIdx.x * TPB + threadIdx.x;
    int y = p >> 8, x = p & 255;
    float acc = ob[0];
    #pragma unroll
    for (int ky = 0; ky < 3; ++ky)
        #pragma unroll
        for (int kx = 0; kx < 3; ++kx) {
            const unsigned short* ip = vI + (size_t)((y + ky - 1) * 258 + (x + kx - 1)) * 64;
            int wb = ky * 3 + kx;
            for (int c = 0; c < 64; c += 4) {
                ushort4 uv = *(const ushort4*)(ip + c);
                acc += bf2f(uv.x) * wl[c * 9 + wb] + bf2f(uv.y) * wl[(c + 1) * 9 + wb]
                     + bf2f(uv.z) * wl[(c + 2) * 9 + wb] + bf2f(uv.w) * wl[(c + 3) * 9 + wb];
            }
        }
    out[p] = acc;
}

static inline TapOffs mk_toffs(int W2, int Cs) {
    TapOffs t;
    for (int ky = 0; ky < 3; ++ky)
        for (int kx = 0; kx < 3; ++kx)
            t.o[ky * 3 + kx] = ((ky - 1) * W2 + (kx - 1)) * Cs;
    return t;
}
static inline TapOffs zero_toffs() { TapOffs t = {}; return t; }

extern "C" void kernel_launch(void* const* d_in, const int* in_sizes, int n_in,
                              void* d_out, int out_size, void* d_ws, size_t ws_size,
                              hipStream_t stream) {
    const float* x    = (const float*)d_in[0];
    const float* d1w1 = (const float*)d_in[1];  const float* d1b1 = (const float*)d_in[2];
    const float* d1w2 = (const float*)d_in[3];  const float* d1b2 = (const float*)d_in[4];
    const float* d2w1 = (const float*)d_in[5];  const float* d2b1 = (const float*)d_in[6];
    const float* d2w2 = (const float*)d_in[7];  const float* d2b2 = (const float*)d_in[8];
    const float* md1w = (const float*)d_in[9];  const float* md1b = (const float*)d_in[10];
    const float* md2w = (const float*)d_in[11]; const float* md2b = (const float*)d_in[12];
    const float* mbw  = (const float*)d_in[13]; const float* mbb  = (const float*)d_in[14];
    const float* mu1w = (const float*)d_in[15]; const float* mu1b = (const float*)d_in[16];
    const float* mu2w = (const float*)d_in[17]; const float* mu2b = (const float*)d_in[18];
    const float* u3tw = (const float*)d_in[19]; const float* u3tb = (const float*)d_in[20];
    const float* u3w1 = (const float*)d_in[21]; const float* u3b1 = (const float*)d_in[22];
    const float* u3w2 = (const float*)d_in[23]; const float* u3b2 = (const float*)d_in[24];
    const float* u4tw = (const float*)d_in[25]; const float* u4tb = (const float*)d_in[26];
    const float* u4w1 = (const float*)d_in[27]; const float* u4b1 = (const float*)d_in[28];
    const float* u4w2 = (const float*)d_in[29]; const float* u4b2 = (const float*)d_in[30];
    const float* ow   = (const float*)d_in[31]; const float* ob   = (const float*)d_in[32];
    float* out = (float*)d_out;

    unsigned short* W = (unsigned short*)d_ws;

    // ---- arena layout (elem offsets, bf16) ----
    const size_t XCOL = 0;                       // 2,097,152  (RegionA)
    const size_t A1   = 2097152;                 // 4,260,096  (RegionA)
    const size_t XB   = 0;                       // 4,521,984  (RegionA reuse)
    const size_t CAT4 = 6357248;                 // 8,520,192
    const size_t RB   = 14877440;                // RegionB 8,520,192
    const size_t P1   = RB;                      // 1,081,600
    const size_t T2   = RB + 1081600;            // 2,163,200
    const size_t XC   = RB;                      // 2,260,992
    const size_t V4A  = RB;                      // 4,260,096
    const size_t V4B  = RB + 4260096;            // 4,260,096
    const size_t CAT3 = 23397632;                // 4,326,400
    const size_t AGG  = 27724032;                // 4,521,984
    const size_t V3A  = 32246016;                // 2,163,200
    const size_t V3B  = 34409216;                // 2,163,200
    const size_t X0   = 36572416;                // 565,248
    const size_t BP1  = 37137664;                // 1,130,496
    const size_t BP2  = 38268160;                // 2,260,992
    const size_t XD   = 39398656;                // 1,130,496
    const size_t WP   = 40529152;                // packed weights 2,320,384
    // total 42,849,536 elems = 85.7 MB

    // interior origins
    const size_t a1I   = A1 + 259 * 64;
    const size_t cat4I = CAT4 + 259 * 128;
    const size_t p1I   = P1 + 131 * 64;
    const size_t t2I   = T2 + 131 * 128;
    const size_t cat3I = CAT3 + 131 * 256;
    const size_t v3aI  = V3A + 131 * 128;
    const size_t v3bI  = V3B + 131 * 128;
    const size_t v4aI  = V4A + 259 * 64;
    const size_t v4bI  = V4B + 259 * 64;
    const size_t X0I   = X0 + 67 * 128;
    const size_t XdI   = XD + 67 * 256;

    dim3 blk(TPB);
    // zero activation arena (pad rings, conv1 K-pad, node pad rows)
    hipMemsetAsync(d_ws, 0, WP * 2, stream);

    // ---- weight packing ----
    struct PK { const float* w; size_t off; int mode, KC, NT, K, N, T; };
    const PK pk[15] = {
        { d1w1, WP + 0,       3, 1,  4,  32,   64,  1 },
        { d1w2, WP + 2048,    0, 2,  4,  64,   64,  9 },
        { d2w1, WP + 38912,   0, 2,  8,  64,   128, 9 },
        { d2w2, WP + 112640,  0, 4,  8,  128,  128, 9 },
        { md1w, WP + 260096,  1, 4,  16, 128,  256, 1 },
        { md2w, WP + 292864,  1, 8,  32, 256,  512, 1 },
        { mbw,  WP + 423936,  1, 16, 64, 512,  1024, 1 },
        { mu1w, WP + 948224,  1, 32, 32, 1024, 512, 1 },
        { mu2w, WP + 1472512, 1, 16, 16, 512,  256, 1 },
        { u3tw, WP + 1603584, 2, 8,  8,  256,  128, 4 },
        { u3w1, WP + 1734656, 0, 8,  8,  256,  128, 9 },
        { u3w2, WP + 2029568, 0, 4,  8,  128,  128, 9 },
        { u4tw, WP + 2177024, 2, 4,  4,  128,  64,  4 },
        { u4w1, WP + 2209792, 0, 4,  4,  128,  64,  9 },
        { u4w2, WP + 2283520, 0, 2,  4,  64,   64,  9 },
    };
    for (int i = 0; i < 15; ++i) {
        int total = pk[i].T * pk[i].KC * pk[i].NT * 512;
        k_pack<<<dim3((total + TPB - 1) / TPB), blk, 0, stream>>>(
            pk[i].w, W + pk[i].off, pk[i].mode, pk[i].KC, pk[i].NT, pk[i].K, pk[i].N, total);
    }

    // ---- encoder ----
    k_im2col<<<dim3(65536 * 32 / TPB), blk, 0, stream>>>(x, W + XCOL);
    k_gemm<<<dim3(1024, 1), blk, 0, stream>>>(W + XCOL, W + WP, d1b1, nullptr, 0,
        W + a1I, 32, 8192, 4, 64, 258 * 64, 1, 1, zero_toffs(), 4, 1);
    k_gemm<<<dim3(1024, 1), blk, 0, stream>>>(W + a1I, W + WP + 2048, d1b2, nullptr, 0,
        W + cat4I, 64, 258 * 64, 4, 128, 258 * 128, 2, 9, mk_toffs(258, 64), 4, 1);
    k_maxpool<<<dim3(128 * 128 * 16 / TPB), blk, 0, stream>>>(
        W + cat4I, W + p1I, 128, 16, 128, 258 * 128, 64, 130 * 64, 128 * 128 * 16);
    k_gemm<<<dim3(256, 2), blk, 0, stream>>>(W + p1I, W + WP + 38912, d2b1, nullptr, 0,
        W + t2I, 64, 130 * 64, 2, 128, 130 * 128, 2, 9, mk_toffs(130, 64), 8, 1);
    k_gemm<<<dim3(256, 2), blk, 0, stream>>>(W + t2I, W + WP + 112640, d2b2, nullptr, 0,
        W + cat3I, 128, 130 * 128, 2, 256, 130 * 256, 4, 9, mk_toffs(130, 128), 8, 1);
    k_maxpool<<<dim3(64 * 64 * 32 / TPB), blk, 0, stream>>>(
        W + cat3I, W + X0I, 64, 32, 256, 130 * 256, 128, 66 * 128, 64 * 64 * 32);

    // ---- GNN on 66x66 padded grid ----
    k_gagg<<<dim3((4356 * 32 + TPB - 1) / TPB), blk, 0, stream>>>(W + X0, W + AGG, 128, 4356 * 32);
    k_gemm<<<dim3(69, 4), blk, 0, stream>>>(W + AGG, W + WP + 260096, md1b, nullptr, 0,
        W + BP1, 128, 0, 69, 256, 0, 4, 1, zero_toffs(), 16, 1);
    k_gagg<<<dim3((4356 * 64 + TPB - 1) / TPB), blk, 0, stream>>>(W + BP1, W + AGG, 256, 4356 * 64);
    k_gemm<<<dim3(69, 8), blk, 0, stream>>>(W + AGG, W + WP + 292864, md2b, nullptr, 0,
        W + BP2, 256, 0, 69, 512, 0, 8, 1, zero_toffs(), 32, 1);
    k_gagg<<<dim3((4356 * 128 + TPB - 1) / TPB), blk, 0, stream>>>(W + BP2, W + AGG, 512, 4356 * 128);
    k_gemm<<<dim3(69, 16), blk, 0, stream>>>(W + AGG, W + WP + 423936, mbb, nullptr, 0,
        W + XB, 512, 0, 69, 1024, 0, 16, 1, zero_toffs(), 64, 1);
    k_gagg<<<dim3((4356 * 256 + TPB - 1) / TPB), blk, 0, stream>>>(W + XB, W + AGG, 1024, 4356 * 256);
    k_gemm<<<dim3(69, 8), blk, 0, stream>>>(W + AGG, W + WP + 948224, mu1b, W + BP2, 512,
        W + XC, 1024, 0, 69, 512, 0, 32, 1, zero_toffs(), 32, 1);
    k_gagg<<<dim3((4356 * 128 + TPB - 1) / TPB), blk, 0, stream>>>(W + XC, W + AGG, 512, 4356 * 128);
    k_gemm<<<dim3(69, 4), blk, 0, stream>>>(W + AGG, W + WP + 1472512, mu2b, W + BP1, 256,
        W + XD, 512, 0, 69, 256, 0, 16, 1, zero_toffs(), 16, 1);

    // ---- decoder stage 3 ----
    for (int dy = 0; dy < 2; ++dy)
        for (int dx = 0; dx < 2; ++dx) {
            int tp = (1 - dy) * 2 + (1 - dx);   // jax conv_transpose tap flip
            k_gemm<<<dim3(64, 2), blk, 0, stream>>>(
                W + XdI, W + WP + 1603584 + (size_t)tp * 8 * 8 * 512, u3tb, nullptr, 0,
                W + cat3I + (size_t)(dy * 130 + dx) * 256 + 128,
                256, 66 * 256, 1, 512, 2 * 130 * 256, 8, 1, zero_toffs(), 8, 0);
        }
    k_gemm<<<dim3(256, 2), blk, 0, stream>>>(W + cat3I, W + WP + 1734656, u3b1, nullptr, 0,
        W + v3aI, 256, 130 * 256, 2, 128, 130 * 128, 8, 9, mk_toffs(130, 256), 8, 1);
    k_gemm<<<dim3(256, 2), blk, 0, stream>>>(W + v3aI, W + WP + 2029568, u3b2, nullptr, 0,
        W + v3bI, 128, 130 * 128, 2, 128, 130 * 128, 4, 9, mk_toffs(130, 128), 8, 1);

    // ---- decoder stage 4 ----
    k_zero_ring<<<dim3((65792 + TPB - 1) / TPB), blk, 0, stream>>>(W + V4A, 258, 258, 64, 65792);
    for (int dy = 0; dy < 2; ++dy)
        for (int dx = 0; dx < 2; ++dx) {
            int tp = (1 - dy) * 2 + (1 - dx);
            k_gemm<<<dim3(256, 1), blk, 0, stream>>>(
                W + v3bI, W + WP + 2177024 + (size_t)tp * 4 * 4 * 512, u4tb, nullptr, 0,
                W + cat4I + (size_t)(dy * 258 + dx) * 128 + 64,
                128, 130 * 128, 2, 256, 2 * 258 * 128, 4, 1, zero_toffs(), 4, 0);
        }
    k_gemm<<<dim3(1024, 1), blk, 0, stream>>>(W + cat4I, W + WP + 2209792, u4b1, nullptr, 0,
        W + v4aI, 128, 258 * 128, 4, 64, 258 * 64, 4, 9, mk_toffs(258, 128), 4, 1);
    k_gemm<<<dim3(1024, 1), blk, 0, stream>>>(W + v4aI, W + WP + 2283520, u4b2, nullptr, 0,
        W + v4bI, 64, 258 * 64, 4, 64, 258 * 64, 2, 9, mk_toffs(258, 64), 4, 1);

    // ---- output conv ----
    k_outconv<<<dim3(256), blk, 0, stream>>>(W + v4bI, ow, ob, out);
}

// Round 3
// 457.703 us; speedup vs baseline: 21.3432x; 1.1165x over previous
//
#include <hip/hip_runtime.h>
#include <cstddef>

#define TPB 256

typedef __attribute__((ext_vector_type(8))) short short8;
typedef __attribute__((ext_vector_type(4))) float f32x4;

__device__ inline unsigned short f2bf(float f) {
    unsigned int u = __builtin_bit_cast(unsigned int, f);
    u += 0x7fffu + ((u >> 16) & 1u);
    return (unsigned short)(u >> 16);
}
__device__ inline float bf2f(unsigned short h) {
    unsigned int u = ((unsigned int)h) << 16;
    return __builtin_bit_cast(float, u);
}

struct TapOffs { int o[9]; };

// ---------------------------------------------------------------------------
// Generic MFMA GEMM, MW m-fragments per wave (block tile = MW*64 m x 64 n).
// A: bf16 channels-last, row pitch AP, channel stride Cs, image width Wimg
// (m -> (y = m/Wimg, x = m%Wimg); 16-px fragments never cross rows since
// Wimg % 16 == 0). Wf packed so each lane's B-frag is one contiguous 16B load.
// ct=1: fused convT — blockIdx.z = tap, output shifted by parity (dy,dx).
// mfma_f32_16x16x32_bf16: A[m=lane&15][k=(lane>>4)*8+j], B[k][n same],
// D: col(n)=lane&15, row(m)=(lane>>4)*4+reg.
// ---------------------------------------------------------------------------
template<int MW, int KC>
__global__ __launch_bounds__(TPB) void k_gemm(
    const unsigned short* __restrict__ A0, const unsigned short* __restrict__ Wf,
    const float* __restrict__ bias, const unsigned short* __restrict__ resid, int RS,
    unsigned short* __restrict__ O0,
    int Cs, int AP, int Wimg, int OMS, int OP,
    int T, TapOffs toffs, int NTtot, int relu, int ct, int ctDy, int ctDx)
{
    int lane = threadIdx.x & 63, wave = threadIdx.x >> 6;
    int ml = lane & 15, kq = lane >> 4;
    int nb = blockIdx.y;

    const unsigned short* Wb = Wf;
    unsigned short* Ob = O0;
    if (ct) {
        int tp = blockIdx.z;
        Wb += (size_t)(tp * KC) * NTtot * 512;
        int dy = 1 - (tp >> 1), dx = 1 - (tp & 1);   // jax conv_transpose tap flip
        Ob += (size_t)dy * ctDy + (size_t)dx * ctDx;
    }
    const unsigned short* WbB = Wb + (size_t)(nb * 4) * 512 + lane * 8;

    int fy[MW], fx[MW];
    const unsigned short* Af[MW];
    #pragma unroll
    for (int f = 0; f < MW; ++f) {
        int mf = (blockIdx.x * 4 + wave) * (16 * MW) + f * 16;
        int y = mf / Wimg, x = mf - y * Wimg;
        fy[f] = y; fx[f] = x;
        Af[f] = A0 + (size_t)y * AP + (size_t)(x + ml) * Cs + kq * 8;
    }

    f32x4 acc[MW][4];
    #pragma unroll
    for (int f = 0; f < MW; ++f)
        #pragma unroll
        for (int nt = 0; nt < 4; ++nt) acc[f][nt] = (f32x4){0.f, 0.f, 0.f, 0.f};

    for (int tp = 0; tp < T; ++tp) {
        int toff = toffs.o[tp];
        const unsigned short* Wt = WbB + (size_t)(tp * KC) * NTtot * 512;
        #pragma unroll
        for (int q = 0; q < KC; ++q) {
            short8 b[4];
            #pragma unroll
            for (int nt = 0; nt < 4; ++nt)
                b[nt] = *(const short8*)(Wt + (size_t)q * NTtot * 512 + nt * 512);
            short8 a[MW];
            #pragma unroll
            for (int f = 0; f < MW; ++f)
                a[f] = *(const short8*)(Af[f] + toff + q * 32);
            #pragma unroll
            for (int f = 0; f < MW; ++f)
                #pragma unroll
                for (int nt = 0; nt < 4; ++nt)
                    acc[f][nt] = __builtin_amdgcn_mfma_f32_16x16x32_bf16(a[f], b[nt], acc[f][nt], 0, 0, 0);
        }
    }

    #pragma unroll
    for (int f = 0; f < MW; ++f) {
        unsigned short* Ot = Ob + (size_t)fy[f] * OP + (size_t)(fx[f] + kq * 4) * OMS + (size_t)nb * 64;
        int mg0 = (blockIdx.x * 4 + wave) * (16 * MW) + f * 16 + kq * 4;
        #pragma unroll
        for (int nt = 0; nt < 4; ++nt) {
            int ng = nb * 64 + nt * 16 + ml;
            float bv = bias[ng];
            #pragma unroll
            for (int r = 0; r < 4; ++r) {
                float v = acc[f][nt][r] + bv;
                if (relu) v = fmaxf(v, 0.f);
                if (resid) v += bf2f(resid[(size_t)(mg0 + r) * RS + ng]);
                Ot[(size_t)r * OMS + nt * 16 + ml] = f2bf(v);
            }
        }
    }
}

// ---------------- fused weight packing (all 15 tensors, one dispatch) -------
// modes: 0 conv OIHW T=9 | 1 node [K][N] | 2 convT HWIO T=4 | 3 conv1 K=32 pad
struct PackArgs {
    const float* w[15];
    int cum[16];            // cumulative elem starts (contiguous dst)
    int mode[15], KC[15], NT[15], K[15], N[15];
};
__global__ __launch_bounds__(TPB) void k_pack_all(
    PackArgs pa, unsigned short* __restrict__ dst, int total)
{
    int idx = blockIdx.x * TPB + threadIdx.x;
    if (idx >= total) return;
    int e = 0;
    #pragma unroll
    for (int i = 1; i < 15; ++i) e += (idx >= pa.cum[i]);
    int local = idx - pa.cum[e];
    const float* w = pa.w[e];
    int KC = pa.KC[e], NT = pa.NT[e], K = pa.K[e], N = pa.N[e], mode = pa.mode[e];

    int j = local & 7, l = (local >> 3) & 63;
    int r = local >> 9;
    int ntg = r % NT; int r2 = r / NT;
    int q = r2 % KC; int tp = r2 / KC;
    int k = q * 32 + (l >> 4) * 8 + j;
    int n = ntg * 16 + (l & 15);
    float v = 0.f;
    if (mode == 0) { int ky = tp / 3, kx = tp % 3; v = w[(size_t)(n * K + k) * 9 + ky * 3 + kx]; }
    else if (mode == 1) { v = w[(size_t)k * N + n]; }
    else if (mode == 2) { v = w[((size_t)tp * K + k) * N + n]; }
    else { if (k < 27) { int tap = k / 3, c = k % 3; int ky = tap / 3, kx = tap % 3;
                         v = w[((n * 3 + c) * 3 + ky) * 3 + kx]; } }
    dst[idx] = f2bf(v);
}

// ---------------- fused pad-ring zeroing (all buffers, one dispatch) --------
struct ZArgs { int off[10]; int cum[11]; int W2[10]; int H2[10]; int Cs[10]; };
__global__ __launch_bounds__(TPB) void k_zero_all(
    ZArgs za, unsigned short* __restrict__ W, int total)
{
    int idx = blockIdx.x * TPB + threadIdx.x;
    if (idx >= total) return;
    int e = 0;
    #pragma unroll
    for (int i = 1; i < 10; ++i) e += (idx >= za.cum[i]);
    int local = idx - za.cum[e];
    int W2 = za.W2[e], H2 = za.H2[e], Cs = za.Cs[e];
    int topbot = 2 * W2 * Cs;
    int iy, ix, c;
    if (local < topbot) {
        int row = local / (W2 * Cs); int rest = local - row * (W2 * Cs);
        iy = row ? (H2 - 1) : 0; ix = rest / Cs; c = rest - (rest / Cs) * Cs;
    } else {
        int idx2 = local - topbot;
        int per = (H2 - 2) * Cs;
        int side = idx2 / per; int rest = idx2 - side * per;
        iy = 1 + rest / Cs; ix = side ? (W2 - 1) : 0; c = rest - (rest / Cs) * Cs;
    }
    W[(size_t)za.off[e] + ((size_t)iy * W2 + ix) * Cs + c] = 0;
}

// ---------------- conv1 im2col: x fp32 [3][256][256] -> xcol bf16 [65536][32]
__global__ __launch_bounds__(TPB) void k_im2col(
    const float* __restrict__ x, unsigned short* __restrict__ xcol)
{
    int idx = blockIdx.x * TPB + threadIdx.x;
    if (idx >= 65536 * 32) return;
    int k = idx & 31, m = idx >> 5;
    int y = m >> 8, xx = m & 255;
    float v = 0.f;
    if (k < 27) {
        int tap = k / 3, c = k - tap * 3;
        int ty = tap / 3, tx = tap % 3;
        int yy = y + ty - 1, xp = xx + tx - 1;
        if (yy >= 0 && yy < 256 && xp >= 0 && xp < 256)
            v = x[c * 65536 + yy * 256 + xp];
    }
    xcol[idx] = f2bf(v);
}

// ---------------- maxpool 2x2 channels-last (strided in/out) ----------------
__global__ __launch_bounds__(TPB) void k_maxpool(
    const unsigned short* __restrict__ inI, unsigned short* __restrict__ outI,
    int Wo, int C4, int CsIn, int inPitch, int CsOut, int outPitch, int total)
{
    int idx = blockIdx.x * TPB + threadIdx.x;
    if (idx >= total) return;
    int c4 = idx % C4; int p = idx / C4;
    int x = p % Wo, y = p / Wo;
    const unsigned short* ip = inI + (size_t)(2 * y) * inPitch + (size_t)(2 * x) * CsIn + c4 * 4;
    ushort4 a = *(const ushort4*)(ip);
    ushort4 b = *(const ushort4*)(ip + CsIn);
    ushort4 c = *(const ushort4*)(ip + inPitch);
    ushort4 d = *(const ushort4*)(ip + inPitch + CsIn);
    ushort4 o;
    o.x = f2bf(fmaxf(fmaxf(bf2f(a.x), bf2f(b.x)), fmaxf(bf2f(c.x), bf2f(d.x))));
    o.y = f2bf(fmaxf(fmaxf(bf2f(a.y), bf2f(b.y)), fmaxf(bf2f(c.y), bf2f(d.y))));
    o.z = f2bf(fmaxf(fmaxf(bf2f(a.z), bf2f(b.z)), fmaxf(bf2f(c.z), bf2f(d.z))));
    o.w = f2bf(fmaxf(fmaxf(bf2f(a.w), bf2f(b.w)), fmaxf(bf2f(c.w), bf2f(d.w))));
    *(ushort4*)(outI + (size_t)y * outPitch + (size_t)x * CsOut + c4 * 4) = o;
}

// ---------------- graph aggregation on 66x66 grid, node-major bf16 ----------
__global__ __launch_bounds__(TPB) void k_gagg(
    const unsigned short* __restrict__ X, unsigned short* __restrict__ agg,
    int C, int total)
{
    int idx = blockIdx.x * TPB + threadIdx.x;
    if (idx >= total) return;
    int C4 = C >> 2;
    int c4 = idx % C4; int n = idx / C4;
    int i = n / 66, j = n - i * 66;
    size_t base = (size_t)n * C + c4 * 4;
    ushort4 s = *(const ushort4*)(X + base);
    float v0 = bf2f(s.x), v1 = bf2f(s.y), v2 = bf2f(s.z), v3 = bf2f(s.w);
    float cnt = 1.f;
    if (i > 0)  { ushort4 u = *(const ushort4*)(X + base - (size_t)66 * C);
                  v0 += bf2f(u.x); v1 += bf2f(u.y); v2 += bf2f(u.z); v3 += bf2f(u.w); cnt += 1.f; }
    if (i < 65) { ushort4 u = *(const ushort4*)(X + base + (size_t)66 * C);
                  v0 += bf2f(u.x); v1 += bf2f(u.y); v2 += bf2f(u.z); v3 += bf2f(u.w); cnt += 1.f; }
    if (j > 0)  { ushort4 u = *(const ushort4*)(X + base - C);
                  v0 += bf2f(u.x); v1 += bf2f(u.y); v2 += bf2f(u.z); v3 += bf2f(u.w); cnt += 1.f; }
    if (j < 65) { ushort4 u = *(const ushort4*)(X + base + C);
                  v0 += bf2f(u.x); v1 += bf2f(u.y); v2 += bf2f(u.z); v3 += bf2f(u.w); cnt += 1.f; }
    float inv = 1.f / cnt;
    ushort4 o;
    o.x = f2bf(v0 * inv); o.y = f2bf(v1 * inv); o.z = f2bf(v2 * inv); o.w = f2bf(v3 * inv);
    *(ushort4*)(agg + base) = o;
}

// ---------------- final conv 64->1, fp32 out --------------------------------
__global__ __launch_bounds__(TPB) void k_outconv(
    const unsigned short* __restrict__ vI, const float* __restrict__ ow,
    const float* __restrict__ ob, float* __restrict__ out)
{
    __shared__ float wl[576];
    for (int i = threadIdx.x; i < 576; i += TPB) wl[i] = ow[i];
    __syncthreads();
    int p = blockIdx.x * TPB + threadIdx.x;
    int y = p >> 8, x = p & 255;
    float acc = ob[0];
    #pragma unroll
    for (int ky = 0; ky < 3; ++ky)
        #pragma unroll
        for (int kx = 0; kx < 3; ++kx) {
            const unsigned short* ip = vI + (size_t)((y + ky - 1) * 258 + (x + kx - 1)) * 64;
            int wb = ky * 3 + kx;
            for (int c = 0; c < 64; c += 4) {
                ushort4 uv = *(const ushort4*)(ip + c);
                acc += bf2f(uv.x) * wl[c * 9 + wb] + bf2f(uv.y) * wl[(c + 1) * 9 + wb]
                     + bf2f(uv.z) * wl[(c + 2) * 9 + wb] + bf2f(uv.w) * wl[(c + 3) * 9 + wb];
            }
        }
    out[p] = acc;
}

static inline TapOffs mk_toffs(int W2, int Cs) {
    TapOffs t;
    for (int ky = 0; ky < 3; ++ky)
        for (int kx = 0; kx < 3; ++kx)
            t.o[ky * 3 + kx] = ((ky - 1) * W2 + (kx - 1)) * Cs;
    return t;
}
static inline TapOffs zero_toffs() { TapOffs t = {}; return t; }

extern "C" void kernel_launch(void* const* d_in, const int* in_sizes, int n_in,
                              void* d_out, int out_size, void* d_ws, size_t ws_size,
                              hipStream_t stream) {
    const float* x    = (const float*)d_in[0];
    const float* d1w1 = (const float*)d_in[1];  const float* d1b1 = (const float*)d_in[2];
    const float* d1w2 = (const float*)d_in[3];  const float* d1b2 = (const float*)d_in[4];
    const float* d2w1 = (const float*)d_in[5];  const float* d2b1 = (const float*)d_in[6];
    const float* d2w2 = (const float*)d_in[7];  const float* d2b2 = (const float*)d_in[8];
    const float* md1w = (const float*)d_in[9];  const float* md1b = (const float*)d_in[10];
    const float* md2w = (const float*)d_in[11]; const float* md2b = (const float*)d_in[12];
    const float* mbw  = (const float*)d_in[13]; const float* mbb  = (const float*)d_in[14];
    const float* mu1w = (const float*)d_in[15]; const float* mu1b = (const float*)d_in[16];
    const float* mu2w = (const float*)d_in[17]; const float* mu2b = (const float*)d_in[18];
    const float* u3tw = (const float*)d_in[19]; const float* u3tb = (const float*)d_in[20];
    const float* u3w1 = (const float*)d_in[21]; const float* u3b1 = (const float*)d_in[22];
    const float* u3w2 = (const float*)d_in[23]; const float* u3b2 = (const float*)d_in[24];
    const float* u4tw = (const float*)d_in[25]; const float* u4tb = (const float*)d_in[26];
    const float* u4w1 = (const float*)d_in[27]; const float* u4b1 = (const float*)d_in[28];
    const float* u4w2 = (const float*)d_in[29]; const float* u4b2 = (const float*)d_in[30];
    const float* ow   = (const float*)d_in[31]; const float* ob   = (const float*)d_in[32];
    float* out = (float*)d_out;

    unsigned short* W = (unsigned short*)d_ws;

    // ---- flat arena (elem offsets, bf16), no aliasing; ~109 MB of 256 MB ----
    const size_t XCOL = 0;          // 65536*32     = 2,097,152
    const size_t A1   = 2097152;    // 258*258*64   = 4,260,096
    const size_t CAT4 = 6357248;    // 258*258*128  = 8,520,192
    const size_t P1   = 14877440;   // 130*130*64   = 1,081,600
    const size_t T2   = 15959040;   // 130*130*128  = 2,163,200
    const size_t CAT3 = 18122240;   // 130*130*256  = 4,326,400
    const size_t X0   = 22448640;   // 66*66*128    = 557,568
    const size_t BP1  = 23006208;   // 4608*256     = 1,179,648
    const size_t BP2  = 24185856;   // 4608*512     = 2,359,296
    const size_t XB   = 26545152;   // 4608*1024    = 4,718,592
    const size_t XC   = 31263744;   // 4608*512     = 2,359,296
    const size_t XD   = 33623040;   // 4608*256     = 1,179,648
    const size_t V3A  = 34802688;   // 130*130*128  = 2,163,200
    const size_t V3B  = 36965888;   // 130*130*128  = 2,163,200
    const size_t V4A  = 39129088;   // 258*258*64   = 4,260,096
    const size_t V4B  = 43389184;   // 258*258*64   = 4,260,096
    const size_t AGG  = 47649280;   // 4608*1024    = 4,718,592
    const size_t WP   = 52367872;   // packed weights 2,320,384 -> end 54,688,256

    const size_t a1I   = A1 + 259 * 64;
    const size_t cat4I = CAT4 + 259 * 128;
    const size_t p1I   = P1 + 131 * 64;
    const size_t t2I   = T2 + 131 * 128;
    const size_t cat3I = CAT3 + 131 * 256;
    const size_t X0I   = X0 + 67 * 128;
    const size_t XdI   = XD + 67 * 256;
    const size_t v3aI  = V3A + 131 * 128;
    const size_t v3bI  = V3B + 131 * 128;
    const size_t v4aI  = V4A + 259 * 64;
    const size_t v4bI  = V4B + 259 * 64;

    dim3 blk(TPB);
    const int BIG = 1 << 28;   // Wimg for non-spatial (GNN) gemms

    // ---- fused pad-ring zeroing (1 dispatch, 725,504 elems) ----
    {
        ZArgs za;
        const int off[10] = {(int)A1,(int)CAT4,(int)P1,(int)T2,(int)CAT3,(int)V3A,(int)V3B,(int)V4A,(int)V4B,(int)X0};
        const int w2 [10] = {258,258,130,130,130,130,130,258,258,66};
        const int h2 [10] = {258,258,130,130,130,130,130,258,258,66};
        const int cs [10] = {64,128,64,128,256,128,128,64,64,128};
        int cum = 0;
        for (int i = 0; i < 10; ++i) {
            za.off[i]=off[i]; za.W2[i]=w2[i]; za.H2[i]=h2[i]; za.Cs[i]=cs[i];
            za.cum[i]=cum; cum += (w2[i]*h2[i] - (w2[i]-2)*(h2[i]-2))*cs[i];
        }
        za.cum[10]=cum;
        k_zero_all<<<dim3((cum + TPB - 1) / TPB), blk, 0, stream>>>(za, W, cum);
    }

    // ---- fused weight packing (1 dispatch) ----
    {
        PackArgs pa;
        const float* ws_[15] = {d1w1,d1w2,d2w1,d2w2,md1w,md2w,mbw,mu1w,mu2w,u3tw,u3w1,u3w2,u4tw,u4w1,u4w2};
        const int mode[15] = {3,0,0,0,1,1,1,1,1,2,0,0,2,0,0};
        const int kc [15] = {1,2,2,4,4,8,16,32,16,8,8,4,4,4,2};
        const int nt [15] = {4,4,8,8,16,32,64,32,16,8,8,8,4,4,4};
        const int kk [15] = {32,64,64,128,128,256,512,1024,512,256,256,128,128,128,64};
        const int nn [15] = {64,64,128,128,256,512,1024,512,256,128,128,128,64,64,64};
        const int tt [15] = {1,9,9,9,1,1,1,1,1,4,9,9,4,9,9};
        int cum = 0;
        for (int i = 0; i < 15; ++i) {
            pa.w[i]=ws_[i]; pa.mode[i]=mode[i]; pa.KC[i]=kc[i]; pa.NT[i]=nt[i];
            pa.K[i]=kk[i]; pa.N[i]=nn[i]; pa.cum[i]=cum;
            cum += tt[i]*kc[i]*nt[i]*512;
        }
        pa.cum[15]=cum;    // 2,320,384
        k_pack_all<<<dim3((cum + TPB - 1) / TPB), blk, 0, stream>>>(pa, W + WP, cum);
    }
    // packed weight offsets (same cumulative order)
    const size_t pw_d1w1=WP+0, pw_d1w2=WP+2048, pw_d2w1=WP+38912, pw_d2w2=WP+112640,
        pw_md1=WP+260096, pw_md2=WP+292864, pw_mb=WP+423936, pw_mu1=WP+948224,
        pw_mu2=WP+1472512, pw_u3t=WP+1603584, pw_u3w1=WP+1734656, pw_u3w2=WP+2029568,
        pw_u4t=WP+2177024, pw_u4w1=WP+2209792, pw_u4w2=WP+2283520;

    // ---- encoder ----
    k_im2col<<<dim3(8192), blk, 0, stream>>>(x, W + XCOL);
    k_gemm<2,1><<<dim3(512,1), blk, 0, stream>>>(W + XCOL, W + pw_d1w1, d1b1, nullptr, 0,
        W + a1I, 32, 8192, 256, 64, 258*64, 1, zero_toffs(), 4, 1, 0,0,0);
    k_gemm<2,2><<<dim3(512,1), blk, 0, stream>>>(W + a1I, W + pw_d1w2, d1b2, nullptr, 0,
        W + cat4I, 64, 258*64, 256, 128, 258*128, 9, mk_toffs(258,64), 4, 1, 0,0,0);
    k_maxpool<<<dim3(1024), blk, 0, stream>>>(W + cat4I, W + p1I, 128, 16, 128, 258*128, 64, 130*64, 128*128*16);
    k_gemm<2,2><<<dim3(128,2), blk, 0, stream>>>(W + p1I, W + pw_d2w1, d2b1, nullptr, 0,
        W + t2I, 64, 130*64, 128, 128, 130*128, 9, mk_toffs(130,64), 8, 1, 0,0,0);
    k_gemm<2,4><<<dim3(128,2), blk, 0, stream>>>(W + t2I, W + pw_d2w2, d2b2, nullptr, 0,
        W + cat3I, 128, 130*128, 128, 256, 130*256, 9, mk_toffs(130,128), 8, 1, 0,0,0);
    k_maxpool<<<dim3(512), blk, 0, stream>>>(W + cat3I, W + X0I, 64, 32, 256, 130*256, 128, 66*128, 64*64*32);

    // ---- GNN on 66x66 padded grid (node-major, M covered to 4480 rows) ----
    k_gagg<<<dim3(545), blk, 0, stream>>>(W + X0, W + AGG, 128, 4356*32);
    k_gemm<2,4><<<dim3(35,4), blk, 0, stream>>>(W + AGG, W + pw_md1, md1b, nullptr, 0,
        W + BP1, 128, 0, BIG, 256, 0, 1, zero_toffs(), 16, 1, 0,0,0);
    k_gagg<<<dim3(1089), blk, 0, stream>>>(W + BP1, W + AGG, 256, 4356*64);
    k_gemm<2,8><<<dim3(35,8), blk, 0, stream>>>(W + AGG, W + pw_md2, md2b, nullptr, 0,
        W + BP2, 256, 0, BIG, 512, 0, 1, zero_toffs(), 32, 1, 0,0,0);
    k_gagg<<<dim3(2178), blk, 0, stream>>>(W + BP2, W + AGG, 512, 4356*128);
    k_gemm<2,16><<<dim3(35,16), blk, 0, stream>>>(W + AGG, W + pw_mb, mbb, nullptr, 0,
        W + XB, 512, 0, BIG, 1024, 0, 1, zero_toffs(), 64, 1, 0,0,0);
    k_gagg<<<dim3(4356), blk, 0, stream>>>(W + XB, W + AGG, 1024, 4356*256);
    k_gemm<2,32><<<dim3(35,8), blk, 0, stream>>>(W + AGG, W + pw_mu1, mu1b, W + BP2, 512,
        W + XC, 1024, 0, BIG, 512, 0, 1, zero_toffs(), 32, 1, 0,0,0);
    k_gagg<<<dim3(2178), blk, 0, stream>>>(W + XC, W + AGG, 512, 4356*128);
    k_gemm<2,16><<<dim3(35,4), blk, 0, stream>>>(W + AGG, W + pw_mu2, mu2b, W + BP1, 256,
        W + XD, 512, 0, BIG, 256, 0, 1, zero_toffs(), 16, 1, 0,0,0);

    // ---- decoder stage 3: fused 4-parity convT + 2 convs ----
    k_gemm<2,8><<<dim3(32,2,4), blk, 0, stream>>>(W + XdI, W + pw_u3t, u3tb, nullptr, 0,
        W + cat3I + 128, 256, 66*256, 64, 512, 2*130*256, 1, zero_toffs(), 8, 0, 1, 130*256, 256);
    k_gemm<2,8><<<dim3(128,2), blk, 0, stream>>>(W + cat3I, W + pw_u3w1, u3b1, nullptr, 0,
        W + v3aI, 256, 130*256, 128, 128, 130*128, 9, mk_toffs(130,256), 8, 1, 0,0,0);
    k_gemm<2,4><<<dim3(128,2), blk, 0, stream>>>(W + v3aI, W + pw_u3w2, u3b2, nullptr, 0,
        W + v3bI, 128, 130*128, 128, 128, 130*128, 9, mk_toffs(130,128), 8, 1, 0,0,0);

    // ---- decoder stage 4 ----
    k_gemm<2,4><<<dim3(128,1,4), blk, 0, stream>>>(W + v3bI, W + pw_u4t, u4tb, nullptr, 0,
        W + cat4I + 64, 128, 130*128, 128, 256, 2*258*128, 1, zero_toffs(), 4, 0, 1, 258*128, 128);
    k_gemm<2,4><<<dim3(512,1), blk, 0, stream>>>(W + cat4I, W + pw_u4w1, u4b1, nullptr, 0,
        W + v4aI, 128, 258*128, 256, 64, 258*64, 9, mk_toffs(258,128), 4, 1, 0,0,0);
    k_gemm<2,2><<<dim3(512,1), blk, 0, stream>>>(W + v4aI, W + pw_u4w2, u4b2, nullptr, 0,
        W + v4bI, 64, 258*64, 256, 64, 258*64, 9, mk_toffs(258,64), 4, 1, 0,0,0);

    // ---- output conv 64->1, fp32 ----
    k_outconv<<<dim3(256), blk, 0, stream>>>(W + v4bI, ow, ob, out);
}